// Round 11
// baseline (114.394 us; speedup 1.0000x reference)
//
#include <hip/hip_runtime.h>
#include <hip/hip_bf16.h>
#include <math.h>

typedef short bf16x8 __attribute__((ext_vector_type(8)));
typedef float f32x4 __attribute__((ext_vector_type(4)));
typedef unsigned int u32x4 __attribute__((ext_vector_type(4)));
typedef unsigned int u32x2 __attribute__((ext_vector_type(2)));

#define SEQ 2048
#define MD 1024
#define DH 128

__device__ __forceinline__ unsigned f2b(float f) {
  union { __hip_bfloat16 h; unsigned short u; } c;
  c.h = __float2bfloat16(f);
  return (unsigned)c.u;
}

// ---------------------------------------------------------------------------
// W prep: W[1024][128] f32 -> Wt[128][1024] bf16 per proj (LDS transpose).
// ---------------------------------------------------------------------------
__global__ __launch_bounds__(256) void wprep_kernel(
    const float* __restrict__ wq, const float* __restrict__ wk,
    const float* __restrict__ wv, __hip_bfloat16* __restrict__ wt)
{
  const int proj = blockIdx.x;   // 3
  const int part = blockIdx.y;   // 8 k-slabs of 128
  const float* __restrict__ w = (proj == 0) ? wq : ((proj == 1) ? wk : wv);
  __hip_bfloat16* __restrict__ o = wt + (size_t)proj * (128 * 1024);
  __shared__ __hip_bfloat16 t[128 * 130];
  const int tid = threadIdx.x;
#pragma unroll 4
  for (int i = 0; i < 64; ++i) {
    int idx = i * 256 + tid;
    int kl = idx >> 7, n = idx & 127;
    t[kl * 130 + n] = __float2bfloat16(w[(size_t)(part * 128 + kl) * 128 + n]);
  }
  __syncthreads();
#pragma unroll 4
  for (int j = 0; j < 64; ++j) {
    int idx = j * 256 + tid;
    int n = idx >> 7, kl = idx & 127;
    o[(size_t)n * 1024 + part * 128 + kl] = t[kl * 130 + n];
  }
}

// ---------------------------------------------------------------------------
// Projection GEMM v8 "many-streams": X[16384,1024] f32 x Wt[128][1024] bf16.
// Theory: delivered BW ~ #independent per-CU issue streams; all prior
// variants had 2-3 blocks/CU and converged at 2.5 TB/s. This one: M=32 x
// N=128, BK=32, LDS 20 KB (2 x 10 KB dbuf: A 2KB + B 8KB) -> grid
// (512,3)=1536 blocks = 6 blocks/CU, 24 waves/CU. Champion schedule
// LD(t+1) -> compute(t) -> ST(t+1) -> barrier; involutive XOR swizzle on
// 64B LDS rows (slot ^= row&3). 4 waves: 2 row-groups x 2 col-groups
// (16 rows x 64 cols each), 4 MFMA/iter/wave, 32 K-iterations.
// ---------------------------------------------------------------------------
__global__ __launch_bounds__(256) void proj_kernel(
    const float* __restrict__ xq, const float* __restrict__ xk, const float* __restrict__ xv,
    const __hip_bfloat16* __restrict__ wt,
    __hip_bfloat16* __restrict__ q_ws, __hip_bfloat16* __restrict__ k_ws,
    __hip_bfloat16* __restrict__ vt_ws)
{
  const int proj = blockIdx.y;
  const float* __restrict__ x = (proj == 0) ? xq : ((proj == 1) ? xk : xv);
  const __hip_bfloat16* __restrict__ w = wt + (size_t)proj * (128 * 1024);
  const int m0 = blockIdx.x * 32;
  const int tid = threadIdx.x;
  const int lane = tid & 63;
  const int wid = tid >> 6;
  const int ll = lane & 15, lh = lane >> 4;
  const int wr = (wid >> 1) * 16;   // wave row group (0/16)
  const int wc = (wid & 1) * 64;    // wave col group (0/64)

  __shared__ char lds[2][10 * 1024];  // per buf: A [32][64B] then B [128][64B]

  const f32x4 zero4 = {0.f, 0.f, 0.f, 0.f};
  f32x4 acc[4];
#pragma unroll
  for (int nf = 0; nf < 4; ++nf) acc[nf] = zero4;

  // staging map (per thread, per iteration: 1 A-load + 2 B-loads, 48B)
  const int a_row = tid >> 3;            // 0..31
  const int a_c4  = (tid & 7) << 2;      // f32 col 0..28
  const int b_n   = tid >> 1;            // 0..127
  const int b_s   = tid & 1;             // 16B slot 0/1 (and +2)

  f32x4 ar;
  u32x4 br0, br1;

#define LD_TILES(KT)                                                          \
  {                                                                           \
    ar = *reinterpret_cast<const f32x4*>(                                     \
        &x[(size_t)(m0 + a_row) * MD + (KT) * 32 + a_c4]);                    \
    br0 = *reinterpret_cast<const u32x4*>(                                    \
        &w[(size_t)b_n * MD + (KT) * 32 + b_s * 8]);                          \
    br1 = *reinterpret_cast<const u32x4*>(                                    \
        &w[(size_t)b_n * MD + (KT) * 32 + (b_s + 2) * 8]);                    \
  }

#define ST_TILES(BUF)                                                         \
  {                                                                           \
    char* Asb = lds[BUF];                                                     \
    char* Bsb = lds[BUF] + 2048;                                              \
    u32x2 pk;                                                                 \
    pk[0] = f2b(ar[0]) | (f2b(ar[1]) << 16);                                  \
    pk[1] = f2b(ar[2]) | (f2b(ar[3]) << 16);                                  \
    *reinterpret_cast<u32x2*>(Asb + a_row * 64 +                              \
        ((a_c4 << 1) ^ ((a_row & 3) << 4))) = pk;                             \
    *reinterpret_cast<u32x4*>(Bsb + b_n * 64 +                                \
        (((b_s) ^ (b_n & 3)) << 4)) = br0;                                    \
    *reinterpret_cast<u32x4*>(Bsb + b_n * 64 +                                \
        (((b_s + 2) ^ (b_n & 3)) << 4)) = br1;                                \
  }

  LD_TILES(0);
  ST_TILES(0);
  __syncthreads();

  const int arow = wr + ll;               // A fragment row for this lane

  for (int kt = 0; kt < 32; ++kt) {
    const int cur = kt & 1;
    if (kt < 31) LD_TILES(kt + 1);        // next-tile loads issued early
    {
      char* Asb = lds[cur];
      char* Bsb = lds[cur] + 2048;
      bf16x8 af = *reinterpret_cast<bf16x8*>(
          Asb + arow * 64 + ((lh ^ (arow & 3)) << 4));
#pragma unroll
      for (int nf = 0; nf < 4; ++nf) {
        int n = wc + nf * 16 + ll;
        bf16x8 bv = *reinterpret_cast<bf16x8*>(
            Bsb + n * 64 + ((lh ^ (n & 3)) << 4));
        acc[nf] = __builtin_amdgcn_mfma_f32_16x16x32_bf16(af, bv, acc[nf], 0, 0, 0);
      }
    }
    if (kt < 31) ST_TILES(1 - cur);       // convert + write next buffer
    __syncthreads();
  }
#undef LD_TILES
#undef ST_TILES

  // ---- epilogue: wave writes rows m0+wr+lh*4+q, cols wc+nf*16+ll ----
  if (proj < 2) {
    __hip_bfloat16* __restrict__ outp = proj ? k_ws : q_ws;
#pragma unroll
    for (int nf = 0; nf < 4; ++nf) {
      int col = wc + nf * 16 + ll;
#pragma unroll
      for (int q = 0; q < 4; ++q) {
        int row = m0 + wr + lh * 4 + q;
        union { __hip_bfloat16 h; unsigned short u; } c;
        c.u = (unsigned short)f2b(acc[nf][q]);
        outp[(size_t)row * DH + col] = c.h;
      }
    }
  } else {
    // V transposed: vt[b][d][s], 4 consecutive s per lane -> 8B store
    const int b = m0 >> 11, sb = m0 & 2047;
#pragma unroll
    for (int nf = 0; nf < 4; ++nf) {
      int s = sb + wr + lh * 4;
      int d = wc + nf * 16 + ll;
      u32x2 pk;
      pk[0] = f2b(acc[nf][0]) | (f2b(acc[nf][1]) << 16);
      pk[1] = f2b(acc[nf][2]) | (f2b(acc[nf][3]) << 16);
      *reinterpret_cast<u32x2*>(&vt_ws[((size_t)b * DH + d) * SEQ + s]) = pk;
    }
  }
}

// ---------------------------------------------------------------------------
// Split-KV causal flash attention (unchanged from Round 4).
// ---------------------------------------------------------------------------
__global__ __launch_bounds__(256) void attn_kernel(
    const __hip_bfloat16* __restrict__ q_ws, const __hip_bfloat16* __restrict__ k_ws,
    const __hip_bfloat16* __restrict__ vt_ws,
    float* __restrict__ pO, float* __restrict__ pml)
{
  const int s = blockIdx.x;
  int qt, c;
  if (s < 8)       { qt = s;                c = 0; }
  else if (s < 24) { int u = s - 8;  qt = 8 + (u >> 1);  c = u & 1; }
  else if (s < 48) { int u = s - 24; qt = 16 + u / 3;    c = u % 3; }
  else             { int u = s - 48; qt = 24 + (u >> 2); c = u & 3; }
  const int b = blockIdx.y;
  const int g = qt >> 3;
  const int slot = b * 80 + (4 * g * (g + 1) + (g + 1) * (qt & 7)) + c;

  const int tid = threadIdx.x;
  const int lane = tid & 63;
  const int wid = tid >> 6;
  const int ll = lane & 15;
  const int lh = lane >> 4;

  __shared__ __hip_bfloat16 Ks[64 * 128];
  __shared__ __hip_bfloat16 Vs[128 * 64];
  __shared__ float Ps[64 * 64];
  char* Ksb = (char*)Ks;
  char* Vsb = (char*)Vs;
  char* Psb = (char*)Ps;

  bf16x8 qf[4];
  {
    const size_t qbase = ((size_t)b * SEQ + qt * 64 + wid * 16 + ll) * DH;
#pragma unroll
    for (int kk = 0; kk < 4; ++kk)
      qf[kk] = *reinterpret_cast<const bf16x8*>(&q_ws[qbase + kk * 32 + lh * 8]);
  }

  const f32x4 zero4 = {0.f, 0.f, 0.f, 0.f};
  float m_r[4], l_r[4];
  f32x4 oacc[8];
#pragma unroll
  for (int q = 0; q < 4; ++q) { m_r[q] = -INFINITY; l_r[q] = 0.f; }
#pragma unroll
  for (int nd = 0; nd < 8; ++nd) oacc[nd] = zero4;

  const float sl2e = 0.0883883476483184f * 1.4426950408889634f;

  const int it0 = c * 8;
  const int it1 = min(qt + 1, it0 + 8);
  for (int it = it0; it < it1; ++it) {
    const int kv0 = it * 64;
#pragma unroll
    for (int i = 0; i < 4; ++i) {
      int id = tid + i * 256;
      int row = id >> 4;
      int cb = (id & 15) << 4;
      u32x4 v = *reinterpret_cast<const u32x4*>(
          &k_ws[((size_t)b * SEQ + kv0 + row) * DH + (cb >> 1)]);
      *reinterpret_cast<u32x4*>(Ksb + row * 256 + (cb ^ ((row & 7) << 4))) = v;
    }
#pragma unroll
    for (int i = 0; i < 4; ++i) {
      int id = tid + i * 256;
      int d = id >> 3;
      int cb = (id & 7) << 4;
      u32x4 v = *reinterpret_cast<const u32x4*>(
          &vt_ws[((size_t)b * DH + d) * SEQ + kv0 + (cb >> 1)]);
      *reinterpret_cast<u32x4*>(Vsb + d * 128 + (cb ^ ((d & 7) << 4))) = v;
    }
    __syncthreads();

    f32x4 sacc[4];
#pragma unroll
    for (int nf = 0; nf < 4; ++nf) sacc[nf] = zero4;
#pragma unroll
    for (int nf = 0; nf < 4; ++nf) {
      int row = nf * 16 + ll;
#pragma unroll
      for (int kk = 0; kk < 4; ++kk) {
        bf16x8 kf = *reinterpret_cast<bf16x8*>(
            Ksb + row * 256 + ((kk * 64 + lh * 16) ^ ((row & 7) << 4)));
        sacc[nf] = __builtin_amdgcn_mfma_f32_16x16x32_bf16(qf[kk], kf, sacc[nf], 0, 0, 0);
      }
    }

    float sv[4][4];
    const int qr0 = qt * 64 + wid * 16 + lh * 4;
#pragma unroll
    for (int nf = 0; nf < 4; ++nf) {
      int kc = kv0 + nf * 16 + ll;
#pragma unroll
      for (int q = 0; q < 4; ++q) {
        float sc = sacc[nf][q] * sl2e;
        sv[nf][q] = (kc <= qr0 + q) ? sc : -INFINITY;
      }
    }

    float p[4][4];
    float alpha[4];
#pragma unroll
    for (int q = 0; q < 4; ++q) {
      float mx = fmaxf(fmaxf(sv[0][q], sv[1][q]), fmaxf(sv[2][q], sv[3][q]));
#pragma unroll
      for (int off = 1; off < 16; off <<= 1)
        mx = fmaxf(mx, __shfl_xor(mx, off));
      float mnew = fmaxf(m_r[q], mx);
      float sum = 0.f;
#pragma unroll
      for (int nf = 0; nf < 4; ++nf) {
        float pv = exp2f(sv[nf][q] - mnew);
        p[nf][q] = pv;
        sum += pv;
      }
#pragma unroll
      for (int off = 1; off < 16; off <<= 1)
        sum += __shfl_xor(sum, off);
      alpha[q] = exp2f(m_r[q] - mnew);
      l_r[q] = l_r[q] * alpha[q] + sum;
      m_r[q] = mnew;
    }
#pragma unroll
    for (int nd = 0; nd < 8; ++nd)
#pragma unroll
      for (int q = 0; q < 4; ++q) oacc[nd][q] *= alpha[q];

#pragma unroll
    for (int nf = 0; nf < 4; ++nf) {
      int kv = nf * 16 + ll;
      f32x4 pv4 = {p[nf][0], p[nf][1], p[nf][2], p[nf][3]};
      *reinterpret_cast<f32x4*>(
          Psb + kv * 256 + ((wid * 64 + lh * 16) ^ ((kv & 7) << 4))) = pv4;
    }

#pragma unroll
    for (int kf = 0; kf < 2; ++kf) {
      float pf[8];
#pragma unroll
      for (int j = 0; j < 8; ++j) {
        int kv = kf * 32 + lh * 8 + j;
        pf[j] = *reinterpret_cast<float*>(
            Psb + kv * 256 + ((wid * 64 + ll * 4) ^ ((kv & 7) << 4)));
      }
      bf16x8 pa;
#pragma unroll
      for (int j = 0; j < 8; ++j) pa[j] = (short)f2b(pf[j]);
#pragma unroll
      for (int nd = 0; nd < 8; ++nd) {
        int d = nd * 16 + ll;
        bf16x8 vf = *reinterpret_cast<bf16x8*>(
            Vsb + d * 128 + ((kf * 64 + lh * 16) ^ ((d & 7) << 4)));
        oacc[nd] = __builtin_amdgcn_mfma_f32_16x16x32_bf16(pa, vf, oacc[nd], 0, 0, 0);
      }
    }
    __syncthreads();
  }

  float* __restrict__ po = pO + (size_t)slot * (64 * 128);
#pragma unroll
  for (int nd = 0; nd < 8; ++nd) {
    int d = nd * 16 + ll;
#pragma unroll
    for (int q = 0; q < 4; ++q) {
      int row = wid * 16 + lh * 4 + q;
      po[row * 128 + d] = oacc[nd][q];
    }
  }
  if (ll == 0) {
    float* __restrict__ pm = pml + (size_t)slot * 128;
#pragma unroll
    for (int q = 0; q < 4; ++q) {
      int row = wid * 16 + lh * 4 + q;
      pm[row * 2 + 0] = m_r[q];
      pm[row * 2 + 1] = l_r[q];
    }
  }
}

// ---------------------------------------------------------------------------
// Combine: merge <=4 partials per (b, qt) with log-sum-exp weights.
// ---------------------------------------------------------------------------
__global__ __launch_bounds__(256) void combine_kernel(
    const float* __restrict__ pO, const float* __restrict__ pml,
    float* __restrict__ out)
{
  const int qt = blockIdx.x;
  const int b = blockIdx.y;
  const int g = qt >> 3;
  const int nc = g + 1;
  const size_t slot0 = (size_t)b * 80 + (4 * g * (g + 1) + (g + 1) * (qt & 7));
  const int tid = threadIdx.x;
  const int r = tid >> 2;
  const int q4 = tid & 3;

  float m[4], l[4];
#pragma unroll
  for (int i = 0; i < 4; ++i) {
    if (i < nc) {
      m[i] = pml[(slot0 + i) * 128 + r * 2 + 0];
      l[i] = pml[(slot0 + i) * 128 + r * 2 + 1];
    } else { m[i] = -INFINITY; l[i] = 0.f; }
  }
  float M = fmaxf(fmaxf(m[0], m[1]), fmaxf(m[2], m[3]));
  float w[4];
  float L = 0.f;
#pragma unroll
  for (int i = 0; i < 4; ++i) {
    w[i] = (i < nc) ? exp2f(m[i] - M) : 0.f;
    L += l[i] * w[i];
  }
  const float inv = 1.0f / L;

  const size_t orow = ((size_t)b * SEQ + qt * 64 + r) * DH;
#pragma unroll
  for (int j = 0; j < 8; ++j) {
    const int col = q4 * 32 + j * 4;
    f32x4 acc = {0.f, 0.f, 0.f, 0.f};
#pragma unroll
    for (int i = 0; i < 4; ++i) {
      if (i < nc) {
        f32x4 v = *reinterpret_cast<const f32x4*>(
            &pO[(slot0 + i) * (64 * 128) + r * 128 + col]);
#pragma unroll
        for (int u = 0; u < 4; ++u) acc[u] += v[u] * w[i];
      }
    }
#pragma unroll
    for (int u = 0; u < 4; ++u) acc[u] *= inv;
    *reinterpret_cast<f32x4*>(&out[orow + col]) = acc;
  }
}

extern "C" void kernel_launch(void* const* d_in, const int* in_sizes, int n_in,
                              void* d_out, int out_size, void* d_ws, size_t ws_size,
                              hipStream_t stream) {
  const float* xq = (const float*)d_in[0];
  const float* xk = (const float*)d_in[1];
  const float* xv = (const float*)d_in[2];
  const float* wq = (const float*)d_in[3];
  const float* wk = (const float*)d_in[4];
  const float* wv = (const float*)d_in[5];

  __hip_bfloat16* q_ws = (__hip_bfloat16*)d_ws;
  __hip_bfloat16* k_ws = q_ws + (size_t)16384 * 128;
  __hip_bfloat16* vt_ws = k_ws + (size_t)16384 * 128;
  __hip_bfloat16* wt_ws = vt_ws + (size_t)16384 * 128;
  float* pO = (float*)((char*)d_ws + 13369344);             // 640*64*128 f32
  float* pml = (float*)((char*)d_ws + 13369344 + 20971520); // 640*64*2 f32
  float* out = (float*)d_out;

  wprep_kernel<<<dim3(3, 8), 256, 0, stream>>>(wq, wk, wv, wt_ws);
  proj_kernel<<<dim3(512, 3), 256, 0, stream>>>(xq, xk, xv, wt_ws,
                                                q_ws, k_ws, vt_ws);
  attn_kernel<<<dim3(80, 8), 256, 0, stream>>>(q_ws, k_ws, vt_ws, pO, pml);
  combine_kernel<<<dim3(32, 8), 256, 0, stream>>>(pO, pml, out);
}

// Round 12
// 95.997 us; speedup vs baseline: 1.1916x; 1.1916x over previous
//
#include <hip/hip_runtime.h>
#include <hip/hip_bf16.h>
#include <math.h>

typedef short bf16x8 __attribute__((ext_vector_type(8)));
typedef float f32x4 __attribute__((ext_vector_type(4)));
typedef unsigned int u32x4 __attribute__((ext_vector_type(4)));
typedef unsigned int u32x2 __attribute__((ext_vector_type(2)));

#define SEQ 2048
#define MD 1024
#define DH 128

__device__ __forceinline__ unsigned f2b(float f) {
  union { __hip_bfloat16 h; unsigned short u; } c;
  c.h = __float2bfloat16(f);
  return (unsigned)c.u;
}

// ---------------------------------------------------------------------------
// W prep: W[1024][128] f32 -> Wt[128][1024] bf16 per proj (LDS transpose).
// ---------------------------------------------------------------------------
__global__ __launch_bounds__(256) void wprep_kernel(
    const float* __restrict__ wq, const float* __restrict__ wk,
    const float* __restrict__ wv, __hip_bfloat16* __restrict__ wt)
{
  const int proj = blockIdx.x;   // 3
  const int part = blockIdx.y;   // 8 k-slabs of 128
  const float* __restrict__ w = (proj == 0) ? wq : ((proj == 1) ? wk : wv);
  __hip_bfloat16* __restrict__ o = wt + (size_t)proj * (128 * 1024);
  __shared__ __hip_bfloat16 t[128 * 130];
  const int tid = threadIdx.x;
#pragma unroll 4
  for (int i = 0; i < 64; ++i) {
    int idx = i * 256 + tid;
    int kl = idx >> 7, n = idx & 127;
    t[kl * 130 + n] = __float2bfloat16(w[(size_t)(part * 128 + kl) * 128 + n]);
  }
  __syncthreads();
#pragma unroll 4
  for (int j = 0; j < 64; ++j) {
    int idx = j * 256 + tid;
    int n = idx >> 7, kl = idx & 127;
    o[(size_t)n * 1024 + part * 128 + kl] = t[kl * 130 + n];
  }
}

// ---------------------------------------------------------------------------
// Projection GEMM — exact Round-4 champion (best timed total 103.1 us).
// M=64 x N=128 tile, BK=64, 256 threads, double-buffered swizzled LDS,
// reg-staged A (f32->bf16) + B (Wt bf16), next-tile loads issued early.
// grid (256, 3) = 768 blocks, 3 blocks/CU.
// ---------------------------------------------------------------------------
__global__ __launch_bounds__(256) void proj_kernel(
    const float* __restrict__ xq, const float* __restrict__ xk, const float* __restrict__ xv,
    const __hip_bfloat16* __restrict__ wt,
    __hip_bfloat16* __restrict__ q_ws, __hip_bfloat16* __restrict__ k_ws,
    __hip_bfloat16* __restrict__ vt_ws)
{
  const int proj = blockIdx.y;
  const float* __restrict__ x = (proj == 0) ? xq : ((proj == 1) ? xk : xv);
  const __hip_bfloat16* __restrict__ w = wt + (size_t)proj * (128 * 1024);
  const int m0 = blockIdx.x * 64;
  const int tid = threadIdx.x;
  const int lane = tid & 63;
  const int wid = tid >> 6;
  const int ll = lane & 15, lh = lane >> 4;
  const int wr = (wid >> 1) * 32;
  const int wc = (wid & 1) * 64;

  __shared__ char lds[2][24 * 1024];

  const f32x4 zero4 = {0.f, 0.f, 0.f, 0.f};
  f32x4 acc[2][4];
#pragma unroll
  for (int mi = 0; mi < 2; ++mi)
#pragma unroll
    for (int nf = 0; nf < 4; ++nf) acc[mi][nf] = zero4;

  const int a_row = tid >> 4;
  const int a_c4  = (tid & 15) << 2;
  const int b_n   = tid >> 3;
  const int b_c   = (tid & 7) << 3;

  f32x4 ar[4];
  u32x4 br[4];

#define LD_TILES(KT)                                                          \
  {                                                                           \
    _Pragma("unroll")                                                         \
    for (int i = 0; i < 4; ++i)                                               \
      ar[i] = *reinterpret_cast<const f32x4*>(                                \
          &x[(size_t)(m0 + a_row + i * 16) * MD + (KT) * 64 + a_c4]);         \
    _Pragma("unroll")                                                         \
    for (int j = 0; j < 4; ++j)                                               \
      br[j] = *reinterpret_cast<const u32x4*>(                                \
          &w[(size_t)(b_n + j * 32) * MD + (KT) * 64 + b_c]);                 \
  }

#define ST_TILES(BUF)                                                         \
  {                                                                           \
    char* Asb = lds[BUF];                                                     \
    char* Bsb = lds[BUF] + 8192;                                              \
    _Pragma("unroll")                                                         \
    for (int i = 0; i < 4; ++i) {                                             \
      int row = a_row + i * 16;                                               \
      u32x2 pk;                                                               \
      pk[0] = f2b(ar[i][0]) | (f2b(ar[i][1]) << 16);                          \
      pk[1] = f2b(ar[i][2]) | (f2b(ar[i][3]) << 16);                          \
      *reinterpret_cast<u32x2*>(Asb + row * 128 +                             \
          ((a_c4 << 1) ^ ((row & 7) << 4))) = pk;                             \
    }                                                                         \
    _Pragma("unroll")                                                         \
    for (int j = 0; j < 4; ++j) {                                             \
      int n = b_n + j * 32;                                                   \
      *reinterpret_cast<u32x4*>(Bsb + n * 128 +                               \
          ((b_c << 1) ^ ((n & 7) << 4))) = br[j];                             \
    }                                                                         \
  }

  LD_TILES(0);
  ST_TILES(0);
  __syncthreads();

  for (int kt = 0; kt < 16; ++kt) {
    const int cur = kt & 1;
    if (kt < 15) LD_TILES(kt + 1);
    {
      char* Asb = lds[cur];
      char* Bsb = lds[cur] + 8192;
#pragma unroll
      for (int kk = 0; kk < 2; ++kk) {
        bf16x8 af[2], bfv[4];
#pragma unroll
        for (int mi = 0; mi < 2; ++mi) {
          int row = wr + mi * 16 + ll;
          af[mi] = *reinterpret_cast<bf16x8*>(
              Asb + row * 128 + ((kk * 64 + lh * 16) ^ ((row & 7) << 4)));
        }
#pragma unroll
        for (int nf = 0; nf < 4; ++nf) {
          int n = wc + nf * 16 + ll;
          bfv[nf] = *reinterpret_cast<bf16x8*>(
              Bsb + n * 128 + ((kk * 64 + lh * 16) ^ ((n & 7) << 4)));
        }
#pragma unroll
        for (int mi = 0; mi < 2; ++mi)
#pragma unroll
          for (int nf = 0; nf < 4; ++nf)
            acc[mi][nf] = __builtin_amdgcn_mfma_f32_16x16x32_bf16(
                af[mi], bfv[nf], acc[mi][nf], 0, 0, 0);
      }
    }
    if (kt < 15) ST_TILES(1 - cur);
    __syncthreads();
  }
#undef LD_TILES
#undef ST_TILES

  if (proj < 2) {
    __hip_bfloat16* __restrict__ outp = proj ? k_ws : q_ws;
#pragma unroll
    for (int mi = 0; mi < 2; ++mi)
#pragma unroll
      for (int nf = 0; nf < 4; ++nf) {
        int col = wc + nf * 16 + ll;
#pragma unroll
        for (int q = 0; q < 4; ++q) {
          int row = m0 + wr + mi * 16 + lh * 4 + q;
          union { __hip_bfloat16 h; unsigned short u; } c;
          c.u = (unsigned short)f2b(acc[mi][nf][q]);
          outp[(size_t)row * DH + col] = c.h;
        }
      }
  } else {
    const int b = m0 >> 11, sb = m0 & 2047;
#pragma unroll
    for (int mi = 0; mi < 2; ++mi)
#pragma unroll
      for (int nf = 0; nf < 4; ++nf) {
        int s = sb + wr + mi * 16 + lh * 4;
        int d = wc + nf * 16 + ll;
        u32x2 pk;
        pk[0] = f2b(acc[mi][nf][0]) | (f2b(acc[mi][nf][1]) << 16);
        pk[1] = f2b(acc[mi][nf][2]) | (f2b(acc[mi][nf][3]) << 16);
        *reinterpret_cast<u32x2*>(&vt_ws[((size_t)b * DH + d) * SEQ + s]) = pk;
      }
  }
}

// ---------------------------------------------------------------------------
// Split-KV causal flash attention (Round-4 structure).
// CHANGE: partials pO written as bf16 (was f32) — halves partial traffic.
// ---------------------------------------------------------------------------
__global__ __launch_bounds__(256) void attn_kernel(
    const __hip_bfloat16* __restrict__ q_ws, const __hip_bfloat16* __restrict__ k_ws,
    const __hip_bfloat16* __restrict__ vt_ws,
    __hip_bfloat16* __restrict__ pO, float* __restrict__ pml)
{
  const int s = blockIdx.x;
  int qt, c;
  if (s < 8)       { qt = s;                c = 0; }
  else if (s < 24) { int u = s - 8;  qt = 8 + (u >> 1);  c = u & 1; }
  else if (s < 48) { int u = s - 24; qt = 16 + u / 3;    c = u % 3; }
  else             { int u = s - 48; qt = 24 + (u >> 2); c = u & 3; }
  const int b = blockIdx.y;
  const int g = qt >> 3;
  const int slot = b * 80 + (4 * g * (g + 1) + (g + 1) * (qt & 7)) + c;

  const int tid = threadIdx.x;
  const int lane = tid & 63;
  const int wid = tid >> 6;
  const int ll = lane & 15;
  const int lh = lane >> 4;

  __shared__ __hip_bfloat16 Ks[64 * 128];
  __shared__ __hip_bfloat16 Vs[128 * 64];
  __shared__ float Ps[64 * 64];
  char* Ksb = (char*)Ks;
  char* Vsb = (char*)Vs;
  char* Psb = (char*)Ps;

  bf16x8 qf[4];
  {
    const size_t qbase = ((size_t)b * SEQ + qt * 64 + wid * 16 + ll) * DH;
#pragma unroll
    for (int kk = 0; kk < 4; ++kk)
      qf[kk] = *reinterpret_cast<const bf16x8*>(&q_ws[qbase + kk * 32 + lh * 8]);
  }

  const f32x4 zero4 = {0.f, 0.f, 0.f, 0.f};
  float m_r[4], l_r[4];
  f32x4 oacc[8];
#pragma unroll
  for (int q = 0; q < 4; ++q) { m_r[q] = -INFINITY; l_r[q] = 0.f; }
#pragma unroll
  for (int nd = 0; nd < 8; ++nd) oacc[nd] = zero4;

  const float sl2e = 0.0883883476483184f * 1.4426950408889634f;

  const int it0 = c * 8;
  const int it1 = min(qt + 1, it0 + 8);
  for (int it = it0; it < it1; ++it) {
    const int kv0 = it * 64;
#pragma unroll
    for (int i = 0; i < 4; ++i) {
      int id = tid + i * 256;
      int row = id >> 4;
      int cb = (id & 15) << 4;
      u32x4 v = *reinterpret_cast<const u32x4*>(
          &k_ws[((size_t)b * SEQ + kv0 + row) * DH + (cb >> 1)]);
      *reinterpret_cast<u32x4*>(Ksb + row * 256 + (cb ^ ((row & 7) << 4))) = v;
    }
#pragma unroll
    for (int i = 0; i < 4; ++i) {
      int id = tid + i * 256;
      int d = id >> 3;
      int cb = (id & 7) << 4;
      u32x4 v = *reinterpret_cast<const u32x4*>(
          &vt_ws[((size_t)b * DH + d) * SEQ + kv0 + (cb >> 1)]);
      *reinterpret_cast<u32x4*>(Vsb + d * 128 + (cb ^ ((d & 7) << 4))) = v;
    }
    __syncthreads();

    f32x4 sacc[4];
#pragma unroll
    for (int nf = 0; nf < 4; ++nf) sacc[nf] = zero4;
#pragma unroll
    for (int nf = 0; nf < 4; ++nf) {
      int row = nf * 16 + ll;
#pragma unroll
      for (int kk = 0; kk < 4; ++kk) {
        bf16x8 kf = *reinterpret_cast<bf16x8*>(
            Ksb + row * 256 + ((kk * 64 + lh * 16) ^ ((row & 7) << 4)));
        sacc[nf] = __builtin_amdgcn_mfma_f32_16x16x32_bf16(qf[kk], kf, sacc[nf], 0, 0, 0);
      }
    }

    float sv[4][4];
    const int qr0 = qt * 64 + wid * 16 + lh * 4;
#pragma unroll
    for (int nf = 0; nf < 4; ++nf) {
      int kc = kv0 + nf * 16 + ll;
#pragma unroll
      for (int q = 0; q < 4; ++q) {
        float sc = sacc[nf][q] * sl2e;
        sv[nf][q] = (kc <= qr0 + q) ? sc : -INFINITY;
      }
    }

    float p[4][4];
    float alpha[4];
#pragma unroll
    for (int q = 0; q < 4; ++q) {
      float mx = fmaxf(fmaxf(sv[0][q], sv[1][q]), fmaxf(sv[2][q], sv[3][q]));
#pragma unroll
      for (int off = 1; off < 16; off <<= 1)
        mx = fmaxf(mx, __shfl_xor(mx, off));
      float mnew = fmaxf(m_r[q], mx);
      float sum = 0.f;
#pragma unroll
      for (int nf = 0; nf < 4; ++nf) {
        float pv = exp2f(sv[nf][q] - mnew);
        p[nf][q] = pv;
        sum += pv;
      }
#pragma unroll
      for (int off = 1; off < 16; off <<= 1)
        sum += __shfl_xor(sum, off);
      alpha[q] = exp2f(m_r[q] - mnew);
      l_r[q] = l_r[q] * alpha[q] + sum;
      m_r[q] = mnew;
    }
#pragma unroll
    for (int nd = 0; nd < 8; ++nd)
#pragma unroll
      for (int q = 0; q < 4; ++q) oacc[nd][q] *= alpha[q];

#pragma unroll
    for (int nf = 0; nf < 4; ++nf) {
      int kv = nf * 16 + ll;
      f32x4 pv4 = {p[nf][0], p[nf][1], p[nf][2], p[nf][3]};
      *reinterpret_cast<f32x4*>(
          Psb + kv * 256 + ((wid * 64 + lh * 16) ^ ((kv & 7) << 4))) = pv4;
    }

#pragma unroll
    for (int kf = 0; kf < 2; ++kf) {
      float pf[8];
#pragma unroll
      for (int j = 0; j < 8; ++j) {
        int kv = kf * 32 + lh * 8 + j;
        pf[j] = *reinterpret_cast<float*>(
            Psb + kv * 256 + ((wid * 64 + ll * 4) ^ ((kv & 7) << 4)));
      }
      bf16x8 pa;
#pragma unroll
      for (int j = 0; j < 8; ++j) pa[j] = (short)f2b(pf[j]);
#pragma unroll
      for (int nd = 0; nd < 8; ++nd) {
        int d = nd * 16 + ll;
        bf16x8 vf = *reinterpret_cast<bf16x8*>(
            Vsb + d * 128 + ((kf * 64 + lh * 16) ^ ((d & 7) << 4)));
        oacc[nd] = __builtin_amdgcn_mfma_f32_16x16x32_bf16(pa, vf, oacc[nd], 0, 0, 0);
      }
    }
    __syncthreads();
  }

  // ---- epilogue: partials as bf16 (rows = wid*16+lh*4+q, cols = nd*16+ll)
  __hip_bfloat16* __restrict__ po = pO + (size_t)slot * (64 * 128);
#pragma unroll
  for (int nd = 0; nd < 8; ++nd) {
    int d = nd * 16 + ll;
#pragma unroll
    for (int q = 0; q < 4; ++q) {
      int row = wid * 16 + lh * 4 + q;
      union { __hip_bfloat16 h; unsigned short u; } cc;
      cc.u = (unsigned short)f2b(oacc[nd][q]);
      po[row * 128 + d] = cc.h;
    }
  }
  if (ll == 0) {
    float* __restrict__ pm = pml + (size_t)slot * 128;
#pragma unroll
    for (int q = 0; q < 4; ++q) {
      int row = wid * 16 + lh * 4 + q;
      pm[row * 2 + 0] = m_r[q];
      pm[row * 2 + 1] = l_r[q];
    }
  }
}

// ---------------------------------------------------------------------------
// Combine: merge <=4 bf16 partials per (b, qt) with log-sum-exp weights.
// ---------------------------------------------------------------------------
__global__ __launch_bounds__(256) void combine_kernel(
    const __hip_bfloat16* __restrict__ pO, const float* __restrict__ pml,
    float* __restrict__ out)
{
  const int qt = blockIdx.x;
  const int b = blockIdx.y;
  const int g = qt >> 3;
  const int nc = g + 1;
  const size_t slot0 = (size_t)b * 80 + (4 * g * (g + 1) + (g + 1) * (qt & 7));
  const int tid = threadIdx.x;
  const int r = tid >> 2;
  const int q4 = tid & 3;

  float m[4], l[4];
#pragma unroll
  for (int i = 0; i < 4; ++i) {
    if (i < nc) {
      m[i] = pml[(slot0 + i) * 128 + r * 2 + 0];
      l[i] = pml[(slot0 + i) * 128 + r * 2 + 1];
    } else { m[i] = -INFINITY; l[i] = 0.f; }
  }
  float M = fmaxf(fmaxf(m[0], m[1]), fmaxf(m[2], m[3]));
  float w[4];
  float L = 0.f;
#pragma unroll
  for (int i = 0; i < 4; ++i) {
    w[i] = (i < nc) ? exp2f(m[i] - M) : 0.f;
    L += l[i] * w[i];
  }
  const float inv = 1.0f / L;

  const size_t orow = ((size_t)b * SEQ + qt * 64 + r) * DH;
#pragma unroll
  for (int j = 0; j < 4; ++j) {
    const int col = q4 * 32 + j * 8;
    float acc[8];
#pragma unroll
    for (int u = 0; u < 8; ++u) acc[u] = 0.f;
#pragma unroll
    for (int i = 0; i < 4; ++i) {
      if (i < nc) {
        bf16x8 v = *reinterpret_cast<const bf16x8*>(
            &pO[(slot0 + i) * (64 * 128) + r * 128 + col]);
#pragma unroll
        for (int u = 0; u < 8; ++u) {
          union { unsigned u32; float f; } cv;
          cv.u32 = ((unsigned)(unsigned short)v[u]) << 16;
          acc[u] += cv.f * w[i];
        }
      }
    }
    f32x4 o0, o1;
#pragma unroll
    for (int u = 0; u < 4; ++u) { o0[u] = acc[u] * inv; o1[u] = acc[4 + u] * inv; }
    *reinterpret_cast<f32x4*>(&out[orow + col]) = o0;
    *reinterpret_cast<f32x4*>(&out[orow + col + 4]) = o1;
  }
}

extern "C" void kernel_launch(void* const* d_in, const int* in_sizes, int n_in,
                              void* d_out, int out_size, void* d_ws, size_t ws_size,
                              hipStream_t stream) {
  const float* xq = (const float*)d_in[0];
  const float* xk = (const float*)d_in[1];
  const float* xv = (const float*)d_in[2];
  const float* wq = (const float*)d_in[3];
  const float* wk = (const float*)d_in[4];
  const float* wv = (const float*)d_in[5];

  __hip_bfloat16* q_ws = (__hip_bfloat16*)d_ws;
  __hip_bfloat16* k_ws = q_ws + (size_t)16384 * 128;
  __hip_bfloat16* vt_ws = k_ws + (size_t)16384 * 128;
  __hip_bfloat16* wt_ws = vt_ws + (size_t)16384 * 128;
  __hip_bfloat16* pO = (__hip_bfloat16*)((char*)d_ws + 13369344); // 640*64*128 bf16
  float* pml = (float*)((char*)d_ws + 13369344 + 10485760);       // 640*64*2 f32
  float* out = (float*)d_out;

  wprep_kernel<<<dim3(3, 8), 256, 0, stream>>>(wq, wk, wv, wt_ws);
  proj_kernel<<<dim3(256, 3), 256, 0, stream>>>(xq, xk, xv, wt_ws,
                                                q_ws, k_ws, vt_ws);
  attn_kernel<<<dim3(80, 8), 256, 0, stream>>>(q_ws, k_ws, vt_ws, pO, pml);
  combine_kernel<<<dim3(32, 8), 256, 0, stream>>>(pO, pml, out);
}